// Round 16
// baseline (214.136 us; speedup 1.0000x reference)
//
#include <hip/hip_runtime.h>
#include <hip/hip_bf16.h>
#include <math.h>

// ---------------- ws layout (float/u32 offsets) ----------------
#define WQ0 0
#define BQ0 320
#define WQ1 384
#define BQ1 4480
#define WQ2 4544
#define BQ2 8640
#define WQ3 8704
#define BQ3 12800
#define WQ4 12864
#define BQ4 12928
#define GT0 12932
#define GT1 13444
#define GT2 15492
// Packed f16 MFMA weight fragments (hi block then lo block), weights scaled
// by 64. Main uses HI ONLY (single-f16 weights; r15: absmax unchanged).
// fi 0..23 = layers 1..3 ((l*2+s)*4+ft), fi 24..27 = layer 0 (K rows 5..31 zero).
#define FRAG_OFF 23684
#define NFRAG 28
// w4 packed as f16 pairs, x64-scaled hi then lo (lo unused as of r16).
#define W4P 38020
#define WSCALE 64.0f
#define WINV   0.015625f

typedef _Float16 f16x8 __attribute__((ext_vector_type(8)));
typedef _Float16 f16x2 __attribute__((ext_vector_type(2)));
typedef float floatx4 __attribute__((ext_vector_type(4)));
typedef float floatx2 __attribute__((ext_vector_type(2)));
typedef unsigned int uintx4 __attribute__((ext_vector_type(4)));

__device__ inline floatx4 mfma16(f16x8 a, f16x8 b, floatx4 c) {
    return __builtin_amdgcn_mfma_f32_16x16x32_f16(a, b, c, 0, 0, 0);
}
__device__ inline floatx2 splat2(float c) { return (floatx2){c, c}; }

// single-inst packed f32->f16 pair conversion (RTZ); returns __fp16x2 —
// bit_cast via auto.
__device__ inline unsigned int pkrtz(float a, float b) {
    auto r = __builtin_amdgcn_cvt_pkrtz(a, b);
    return __builtin_bit_cast(unsigned int, r);
}
// exact RNE pack (prep-side / layer-0 staging)
__device__ inline unsigned int pack_f16(float a, float b) {
    unsigned short ua = __builtin_bit_cast(unsigned short, (_Float16)a);
    unsigned short ub = __builtin_bit_cast(unsigned short, (_Float16)b);
    return (unsigned int)ua | ((unsigned int)ub << 16);
}
__device__ inline f16x8 frag_from(uint2 a, uint2 b) {
    uintx4 u = {a.x, a.y, b.x, b.y};
    return __builtin_bit_cast(f16x8, u);
}
__device__ inline f16x2 h2(unsigned int u) { return __builtin_bit_cast(f16x2, u); }

#if __has_builtin(__builtin_amdgcn_fdot2)
__device__ inline float fdot2f(f16x2 a, f16x2 b, float c) {
    return __builtin_amdgcn_fdot2(a, b, c, false);
}
#else
__device__ inline float fdot2f(f16x2 a, f16x2 b, float c) {
    return fmaf((float)a[0], (float)b[0], fmaf((float)a[1], (float)b[1], c));
}
#endif

// Packed-pair gelu: 0.5*(x + |x|*erf_mag(|x|/sqrt2)), AS 7.1.25 erf (2.5e-5).
__device__ inline floatx2 gelu2(floatx2 x) {
    floatx2 ax = __builtin_elementwise_abs(x);
    floatx2 z  = ax * splat2(0.70710678118654752f);
    floatx2 den = __builtin_elementwise_fma(z, splat2(0.47047f), splat2(1.0f));
    floatx2 t;
    t.x = __builtin_amdgcn_rcpf(den.x);
    t.y = __builtin_amdgcn_rcpf(den.y);
    floatx2 p = __builtin_elementwise_fma(t, splat2(0.7478556f), splat2(-0.0958798f));
    p = __builtin_elementwise_fma(t, p, splat2(0.3480242f));
    p = p * t;
    floatx2 ea = (z * z) * splat2(-1.44269504088896f);
    floatx2 e;
    e.x = __builtin_amdgcn_exp2f(ea.x);
    e.y = __builtin_amdgcn_exp2f(ea.y);
    floatx2 er = __builtin_elementwise_fma(-p, e, splat2(1.0f));
    return __builtin_elementwise_fma(ax, er, x) * splat2(0.5f);
}

__device__ inline float tanh_fast(float x) {
    float e = __builtin_amdgcn_exp2f(x * 2.88539008177793f);
    return fmaf(-2.0f, __builtin_amdgcn_rcpf(e + 1.0f), 1.0f);
}

__device__ void block_minmax(float mn, float mx, float* omn, float* omx,
                             float* smn, float* smx) {
    __syncthreads();
    #pragma unroll
    for (int off = 32; off > 0; off >>= 1) {
        mn = fminf(mn, __shfl_down(mn, off));
        mx = fmaxf(mx, __shfl_down(mx, off));
    }
    int wid = threadIdx.x >> 6, lane = threadIdx.x & 63;
    if (lane == 0) { smn[wid] = mn; smx[wid] = mx; }
    __syncthreads();
    if (threadIdx.x == 0) {
        float a = smn[0], b = smx[0];
        for (int i = 1; i < 4; ++i) { a = fminf(a, smn[i]); b = fmaxf(b, smx[i]); }
        smn[0] = a; smx[0] = b;
    }
    __syncthreads();
    *omn = smn[0]; *omx = smx[0];
}

// _qround forward: round((x-mn)/scale)*scale + mn, scale = max(mx-mn,1e-8)/63
__device__ void quantize_tensor(const float* __restrict__ src, int n,
                                float* __restrict__ dst, float* smn, float* smx) {
    float mn = 3.4e38f, mx = -3.4e38f;
    for (int i = threadIdx.x; i < n; i += blockDim.x) {
        float v = src[i];
        mn = fminf(mn, v); mx = fmaxf(mx, v);
    }
    float gmn, gmx;
    block_minmax(mn, mx, &gmn, &gmx, smn, smx);
    float scale = fmaxf(gmx - gmn, 1e-8f) / 63.0f;
    for (int i = threadIdx.x; i < n; i += blockDim.x) {
        float v = src[i];
        dst[i] = rintf((v - gmn) / scale) * scale + gmn;
    }
}

// ONE prep launch (47 blocks):
//   0..9   : quantize weight/bias tensors into ws
//   10..20 : grid argmax tables
//   21..44 : weight fragments, layers 1..3 (self-contained minmax)
//   45     : weight fragments, layer 0 (4 waves; K rows 5..31 zero)
//   46     : w4 f16-pair pack (x64 scaled)
__global__ void vinr_prep(
    const float* __restrict__ cb0, const float* __restrict__ ind0,
    const float* __restrict__ cb1, const float* __restrict__ ind1,
    const float* __restrict__ cb2, const float* __restrict__ ind2,
    const float* __restrict__ w0, const float* __restrict__ b0,
    const float* __restrict__ w1, const float* __restrict__ b1,
    const float* __restrict__ w2, const float* __restrict__ b2,
    const float* __restrict__ w3, const float* __restrict__ b3,
    const float* __restrict__ w4, const float* __restrict__ b4,
    float* __restrict__ ws)
{
    __shared__ float smn[4], smx[4];
    if (blockIdx.x < 10) {
        switch (blockIdx.x) {
            case 0: quantize_tensor(w0, 320, ws + WQ0, smn, smx); break;
            case 1: quantize_tensor(b0, 64, ws + BQ0, smn, smx); break;
            case 2: quantize_tensor(w1, 4096, ws + WQ1, smn, smx); break;
            case 3: quantize_tensor(b1, 64, ws + BQ1, smn, smx); break;
            case 4: quantize_tensor(w2, 4096, ws + WQ2, smn, smx); break;
            case 5: quantize_tensor(b2, 64, ws + BQ2, smn, smx); break;
            case 6: quantize_tensor(w3, 4096, ws + WQ3, smn, smx); break;
            case 7: quantize_tensor(b3, 64, ws + BQ3, smn, smx); break;
            case 8: quantize_tensor(w4, 64, ws + WQ4, smn, smx); break;
            case 9: quantize_tensor(b4, 1, ws + BQ4, smn, smx); break;
        }
    } else if (blockIdx.x < 21) {
        int r = (int)(blockIdx.x - 10) * 256 + (int)threadIdx.x;
        const float* ind = nullptr; const float* cb = nullptr; float* dst = nullptr;
        if (r < 128)       { ind = ind0 + r * 64;          cb = cb0; dst = ws + GT0 + r * 4; }
        else if (r < 640)  { int rr = r - 128;  ind = ind1 + rr * 64; cb = cb1; dst = ws + GT1 + rr * 4; }
        else if (r < 2688) { int rr = r - 640;  ind = ind2 + rr * 64; cb = cb2; dst = ws + GT2 + rr * 4; }
        if (dst) {
            float best = -3.4e38f; int bi = 0;
            for (int j = 0; j < 64; ++j) {
                float v = ind[j];
                if (v > best) { best = v; bi = j; }
            }
            #pragma unroll
            for (int d = 0; d < 4; ++d) dst[d] = cb[bi * 4 + d];
        }
    } else if (blockIdx.x < 45) {
        if (threadIdx.x < 64) {                        // one wave per frag
            int fi = (int)blockIdx.x - 21;             // 0..23
            int lane = (int)threadIdx.x;
            int l = fi >> 3, s = (fi >> 2) & 1, ft = fi & 3;
            const float* w = (l == 0) ? w1 : (l == 1) ? w2 : w3;
            float mn = 3.4e38f, mx = -3.4e38f;
            for (int i = lane; i < 4096; i += 64) {
                float v = w[i];
                mn = fminf(mn, v); mx = fmaxf(mx, v);
            }
            #pragma unroll
            for (int off = 32; off > 0; off >>= 1) {
                mn = fminf(mn, __shfl_xor(mn, off));
                mx = fmaxf(mx, __shfl_xor(mx, off));
            }
            float scale = fmaxf(mx - mn, 1e-8f) / 63.0f;
            int q = lane >> 4, m15 = lane & 15;
            int n = ft * 16 + m15;
            f16x8 hi;
            #pragma unroll
            for (int j = 0; j < 8; ++j) {
                int k = s * 32 + q * 8 + j;
                float v = w[k * 64 + n];
                v = (rintf((v - mn) / scale) * scale + mn) * WSCALE;
                hi[j] = (_Float16)v;
            }
            f16x8* base = (f16x8*)(ws + FRAG_OFF);
            base[fi * 64 + lane] = hi;
        }
    } else if (blockIdx.x == 45) {
        // layer-0 frags: wave wv -> ft wv; W0 is [5][64], K padded to 32 with zeros.
        int wv = (int)threadIdx.x >> 6;
        int lane = (int)threadIdx.x & 63;
        if (wv < 4) {
            float mn = 3.4e38f, mx = -3.4e38f;
            for (int i = lane; i < 320; i += 64) {
                float v = w0[i];
                mn = fminf(mn, v); mx = fmaxf(mx, v);
            }
            #pragma unroll
            for (int off = 32; off > 0; off >>= 1) {
                mn = fminf(mn, __shfl_xor(mn, off));
                mx = fmaxf(mx, __shfl_xor(mx, off));
            }
            float scale = fmaxf(mx - mn, 1e-8f) / 63.0f;
            int q = lane >> 4, m15 = lane & 15;
            int n = wv * 16 + m15;
            f16x8 hi;
            #pragma unroll
            for (int j = 0; j < 8; ++j) {
                int k = q * 8 + j;
                float v = 0.0f;
                if (k < 5) {
                    float vv = w0[k * 64 + n];
                    v = (rintf((vv - mn) / scale) * scale + mn) * WSCALE;
                }
                hi[j] = (_Float16)v;
            }
            f16x8* base = (f16x8*)(ws + FRAG_OFF);
            base[(24 + wv) * 64 + lane] = hi;
        }
    } else {
        // w4 pack: quantize (self-contained minmax), scale x64, single f16 pairs.
        if (threadIdx.x < 64) {
            int lane = (int)threadIdx.x;
            float v = w4[lane];
            float mn = v, mx = v;
            #pragma unroll
            for (int off = 32; off > 0; off >>= 1) {
                mn = fminf(mn, __shfl_xor(mn, off));
                mx = fmaxf(mx, __shfl_xor(mx, off));
            }
            float scale = fmaxf(mx - mn, 1e-8f) / 63.0f;
            if (lane < 32) {
                float q0 = (rintf((w4[2 * lane] - mn) / scale) * scale + mn) * WSCALE;
                float q1 = (rintf((w4[2 * lane + 1] - mn) / scale) * scale + mn) * WSCALE;
                unsigned int* wsU = (unsigned int*)ws;
                wsU[W4P + lane] = pack_f16(q0, q1);   // hi (RNE) — lo dropped (r16)
            }
        }
    }
}

// 32 points per wave; activations in LDS as packed f16 pairs in B-frag pair
// order (row/point stride 38 u32, zero measured conflicts). Weights: single
// RNE f16 (x64-scaled hi frags only), 56 MFMAs/wave-pass. Layer loop fully
// unrolled. r16: min 8 waves/EU (VGPR<=64) to soak the ~14% issue idle.
#define PSTR 38

__global__ __launch_bounds__(256, 8) void vinr_main(
    const float* __restrict__ x, const float* __restrict__ ws,
    float* __restrict__ out, int N)
{
    __shared__ __align__(16) unsigned int hlds[4 * 32 * PSTR];
    int wave = threadIdx.x >> 6, lane = threadIdx.x & 63;
    int q = lane >> 4, m15 = lane & 15;
    int p = lane & 31, half = lane >> 5;
    unsigned int* slice = hlds + wave * (32 * PSTR);

    int idx = (int)blockIdx.x * 128 + wave * 32 + p;
    int idxc = min(idx, N - 1);
    float2 xr = ((const float2*)x)[idxc];
    float feat  = xr.x;
    float coord = xr.y;

    float g0 = 0.f, g1 = 0.f, g2 = 0.f, g3 = 0.f;
    const int RES[3]  = {128, 512, 2048};
    const int GOFF[3] = {GT0, GT1, GT2};
    #pragma unroll
    for (int gi = 0; gi < 3; ++gi) {
        int res = RES[gi];
        float c = (coord + 1.0f) * 0.5f * (float)(res - 1);
        int left  = min((int)floorf(c), res - 2);
        int right = max((int)ceilf(c), 1);
        float w = c - (float)left;
        const float4* gt = (const float4*)(ws + GOFF[gi]);
        float4 gl = gt[left];
        float4 gr = gt[right];
        float wm = 1.0f - w;
        g0 += wm * gl.x + w * gr.x;
        g1 += wm * gl.y + w * gr.y;
        g2 += wm * gl.z + w * gr.z;
        g3 += wm * gl.w + w * gr.w;
    }

    const f16x8* fh = (const f16x8*)(ws + FRAG_OFF);
    f16x8 zfrag = __builtin_bit_cast(f16x8, (uintx4){0u, 0u, 0u, 0u});

    // stage layer-0 B inputs as f16 pairs: row p slots 0..3 (half 0 only).
    if (half == 0) {
        unsigned int* row = slice + p * PSTR;
        *(uint2*)row       = make_uint2(pack_f16(g0, g1), pack_f16(g2, g3));
        *(uint2*)(row + 2) = make_uint2(pack_f16(feat, 0.0f), 0u);
    }

    // ---- layer 0 (5 -> 64): A = 64*W0^T hi frags (K rows >=5 zero), B = inputs.
    {
        f16x8 Wh[4];
        #pragma unroll
        for (int ft = 0; ft < 4; ++ft)
            Wh[ft] = fh[(24 + ft) * 64 + lane];
        f16x8 B[2];
        #pragma unroll
        for (int pt = 0; pt < 2; ++pt) {
            B[pt] = zfrag;
            if (q == 0) {
                const unsigned int* rp = slice + (pt * 16 + m15) * PSTR;
                B[pt] = frag_from(*(const uint2*)rp, *(const uint2*)(rp + 2));
            }
        }
        floatx4 acc[4][2];
        #pragma unroll
        for (int ft = 0; ft < 4; ++ft)
            #pragma unroll
            for (int pt = 0; pt < 2; ++pt)
                acc[ft][pt] = (floatx4){0.f, 0.f, 0.f, 0.f};
        #pragma unroll
        for (int ft = 0; ft < 4; ++ft)
            #pragma unroll
            for (int pt = 0; pt < 2; ++pt)
                acc[ft][pt] = mfma16(Wh[ft], B[pt], acc[ft][pt]);
        #pragma unroll
        for (int ft = 0; ft < 4; ++ft) {
            float4 b4 = *(const float4*)(ws + BQ0 + ft * 16 + q * 4);
            #pragma unroll
            for (int pt = 0; pt < 2; ++pt) {
                floatx4 av = acc[ft][pt];
                floatx2 a01 = __builtin_elementwise_fma((floatx2){av[0], av[1]},
                                  splat2(WINV), (floatx2){b4.x, b4.y});
                floatx2 a23 = __builtin_elementwise_fma((floatx2){av[2], av[3]},
                                  splat2(WINV), (floatx2){b4.z, b4.w});
                floatx2 v01 = gelu2(a01);
                floatx2 v23 = gelu2(a23);
                *(uint2*)(slice + (pt * 16 + m15) * PSTR + 8 * ft + 2 * q) =
                    make_uint2(pkrtz(v01.x, v01.y), pkrtz(v23.x, v23.y));
            }
        }
    }

    // ---- layers 1..3 (fully unrolled)
    const int BQL[3] = {BQ1, BQ2, BQ3};
    #pragma unroll
    for (int l = 0; l < 3; ++l) {
        floatx4 acc[4][2];
        #pragma unroll
        for (int ft = 0; ft < 4; ++ft)
            #pragma unroll
            for (int pt = 0; pt < 2; ++pt)
                acc[ft][pt] = (floatx4){0.f, 0.f, 0.f, 0.f};

        #pragma unroll
        for (int s = 0; s < 2; ++s) {
            f16x8 Wh[4];
            #pragma unroll
            for (int ft = 0; ft < 4; ++ft)
                Wh[ft] = fh[((l * 2 + s) * 4 + ft) * 64 + lane];
            f16x8 B[2];
            #pragma unroll
            for (int pt = 0; pt < 2; ++pt) {
                const unsigned int* rp =
                    slice + (pt * 16 + m15) * PSTR + 16 * s + 4 * q;
                B[pt] = frag_from(*(const uint2*)rp, *(const uint2*)(rp + 2));
            }
            #pragma unroll
            for (int ft = 0; ft < 4; ++ft)
                #pragma unroll
                for (int pt = 0; pt < 2; ++pt)
                    acc[ft][pt] = mfma16(Wh[ft], B[pt], acc[ft][pt]);
        }
        #pragma unroll
        for (int ft = 0; ft < 4; ++ft) {
            float4 b4 = *(const float4*)(ws + BQL[l] + ft * 16 + q * 4);
            #pragma unroll
            for (int pt = 0; pt < 2; ++pt) {
                floatx4 av = acc[ft][pt];
                floatx2 a01 = __builtin_elementwise_fma((floatx2){av[0], av[1]},
                                  splat2(WINV), (floatx2){b4.x, b4.y});
                floatx2 a23 = __builtin_elementwise_fma((floatx2){av[2], av[3]},
                                  splat2(WINV), (floatx2){b4.z, b4.w});
                floatx2 v01 = gelu2(a01);
                floatx2 v23 = gelu2(a23);
                *(uint2*)(slice + (pt * 16 + m15) * PSTR + 8 * ft + 2 * q) =
                    make_uint2(pkrtz(v01.x, v01.y), pkrtz(v23.x, v23.y));
            }
        }
    }

    // layer 4: half-dot over f16 pairs via v_dot2_f32_f16, combine via shfl.
    {
        const unsigned int* wsU = (const unsigned int*)ws;
        const unsigned int* base = slice + p * PSTR + 16 * half;
        int wb = W4P + 16 * half;
        float ah = 0.0f;
        #pragma unroll
        for (int c = 0; c < 8; ++c) {
            uint2 r = *(const uint2*)(base + 2 * c);
            ah = fdot2f(h2(r.x), h2(wsU[wb + 2 * c]),     ah);
            ah = fdot2f(h2(r.y), h2(wsU[wb + 2 * c + 1]), ah);
        }
        float acc4 = fmaf(ah, WINV, (half == 0) ? ws[BQ4] : 0.0f);
        acc4 += __shfl_xor(acc4, 32);
        if (half == 0 && idx < N) out[idx] = tanh_fast(acc4);
    }
}

extern "C" void kernel_launch(void* const* d_in, const int* in_sizes, int n_in,
                              void* d_out, int out_size, void* d_ws, size_t ws_size,
                              hipStream_t stream) {
    const float* x    = (const float*)d_in[0];
    const float* cb0  = (const float*)d_in[1];
    const float* ind0 = (const float*)d_in[2];
    const float* cb1  = (const float*)d_in[3];
    const float* ind1 = (const float*)d_in[4];
    const float* cb2  = (const float*)d_in[5];
    const float* ind2 = (const float*)d_in[6];
    const float* w0 = (const float*)d_in[7],  * b0 = (const float*)d_in[8];
    const float* w1 = (const float*)d_in[9],  * b1 = (const float*)d_in[10];
    const float* w2 = (const float*)d_in[11], * b2 = (const float*)d_in[12];
    const float* w3 = (const float*)d_in[13], * b3 = (const float*)d_in[14];
    const float* w4 = (const float*)d_in[15], * b4 = (const float*)d_in[16];
    float* ws  = (float*)d_ws;
    float* out = (float*)d_out;

    int N = in_sizes[0] / 2;  // 1<<20

    vinr_prep<<<47, 256, 0, stream>>>(cb0, ind0, cb1, ind1, cb2, ind2,
                                      w0, b0, w1, b1, w2, b2, w3, b3, w4, b4, ws);
    int blocks = (N + 127) / 128;
    vinr_main<<<blocks, 256, 0, stream>>>(x, ws, out, N);
}

// Round 17
// 210.180 us; speedup vs baseline: 1.0188x; 1.0188x over previous
//
#include <hip/hip_runtime.h>
#include <hip/hip_bf16.h>
#include <math.h>

// ---------------- ws layout (float/u32 offsets) ----------------
#define WQ0 0
#define BQ0 320
#define WQ1 384
#define BQ1 4480
#define WQ2 4544
#define BQ2 8640
#define WQ3 8704
#define BQ3 12800
#define WQ4 12864
#define BQ4 12928
#define GT0 12932
#define GT1 13444
#define GT2 15492
// Packed f16 MFMA weight fragments, x64-scaled, single RNE f16 (hi only —
// r15/r16: absmax unchanged vs hi/lo split).
// fi 0..23 = layers 1..3 ((l*2+s)*4+ft), fi 24..27 = layer 0 (K rows 5..31 zero).
#define FRAG_OFF 23684
#define NFRAG 28
// w4 packed as f16 pairs, x64-scaled (single f16).
#define W4P 38020
#define WSCALE 64.0f
#define WINV   0.015625f

typedef _Float16 f16x8 __attribute__((ext_vector_type(8)));
typedef _Float16 f16x2 __attribute__((ext_vector_type(2)));
typedef float floatx4 __attribute__((ext_vector_type(4)));
typedef float floatx2 __attribute__((ext_vector_type(2)));
typedef unsigned int uintx4 __attribute__((ext_vector_type(4)));

__device__ inline floatx4 mfma16(f16x8 a, f16x8 b, floatx4 c) {
    return __builtin_amdgcn_mfma_f32_16x16x32_f16(a, b, c, 0, 0, 0);
}
__device__ inline floatx2 splat2(float c) { return (floatx2){c, c}; }

// single-inst packed f32->f16 pair conversion (RTZ); returns __fp16x2.
__device__ inline unsigned int pkrtz(float a, float b) {
    auto r = __builtin_amdgcn_cvt_pkrtz(a, b);
    return __builtin_bit_cast(unsigned int, r);
}
// exact RNE pack (prep-side / layer-0 staging)
__device__ inline unsigned int pack_f16(float a, float b) {
    unsigned short ua = __builtin_bit_cast(unsigned short, (_Float16)a);
    unsigned short ub = __builtin_bit_cast(unsigned short, (_Float16)b);
    return (unsigned int)ua | ((unsigned int)ub << 16);
}
__device__ inline f16x8 frag_from(uint2 a, uint2 b) {
    uintx4 u = {a.x, a.y, b.x, b.y};
    return __builtin_bit_cast(f16x8, u);
}
__device__ inline f16x2 h2(unsigned int u) { return __builtin_bit_cast(f16x2, u); }

#if __has_builtin(__builtin_amdgcn_fdot2)
__device__ inline float fdot2f(f16x2 a, f16x2 b, float c) {
    return __builtin_amdgcn_fdot2(a, b, c, false);
}
#else
__device__ inline float fdot2f(f16x2 a, f16x2 b, float c) {
    return fmaf((float)a[0], (float)b[0], fmaf((float)a[1], (float)b[1], c));
}
#endif

// Packed-pair gelu: 0.5*(x + |x|*erf_mag(|x|/sqrt2)), AS 7.1.25 erf (2.5e-5).
__device__ inline floatx2 gelu2(floatx2 x) {
    floatx2 ax = __builtin_elementwise_abs(x);
    floatx2 z  = ax * splat2(0.70710678118654752f);
    floatx2 den = __builtin_elementwise_fma(z, splat2(0.47047f), splat2(1.0f));
    floatx2 t;
    t.x = __builtin_amdgcn_rcpf(den.x);
    t.y = __builtin_amdgcn_rcpf(den.y);
    floatx2 p = __builtin_elementwise_fma(t, splat2(0.7478556f), splat2(-0.0958798f));
    p = __builtin_elementwise_fma(t, p, splat2(0.3480242f));
    p = p * t;
    floatx2 ea = (z * z) * splat2(-1.44269504088896f);
    floatx2 e;
    e.x = __builtin_amdgcn_exp2f(ea.x);
    e.y = __builtin_amdgcn_exp2f(ea.y);
    floatx2 er = __builtin_elementwise_fma(-p, e, splat2(1.0f));
    return __builtin_elementwise_fma(ax, er, x) * splat2(0.5f);
}

__device__ inline float tanh_fast(float x) {
    float e = __builtin_amdgcn_exp2f(x * 2.88539008177793f);
    return fmaf(-2.0f, __builtin_amdgcn_rcpf(e + 1.0f), 1.0f);
}

__device__ void block_minmax(float mn, float mx, float* omn, float* omx,
                             float* smn, float* smx) {
    __syncthreads();
    #pragma unroll
    for (int off = 32; off > 0; off >>= 1) {
        mn = fminf(mn, __shfl_down(mn, off));
        mx = fmaxf(mx, __shfl_down(mx, off));
    }
    int wid = threadIdx.x >> 6, lane = threadIdx.x & 63;
    if (lane == 0) { smn[wid] = mn; smx[wid] = mx; }
    __syncthreads();
    if (threadIdx.x == 0) {
        float a = smn[0], b = smx[0];
        for (int i = 1; i < 4; ++i) { a = fminf(a, smn[i]); b = fmaxf(b, smx[i]); }
        smn[0] = a; smx[0] = b;
    }
    __syncthreads();
    *omn = smn[0]; *omx = smx[0];
}

// _qround forward: round((x-mn)/scale)*scale + mn, scale = max(mx-mn,1e-8)/63
__device__ void quantize_tensor(const float* __restrict__ src, int n,
                                float* __restrict__ dst, float* smn, float* smx) {
    float mn = 3.4e38f, mx = -3.4e38f;
    for (int i = threadIdx.x; i < n; i += blockDim.x) {
        float v = src[i];
        mn = fminf(mn, v); mx = fmaxf(mx, v);
    }
    float gmn, gmx;
    block_minmax(mn, mx, &gmn, &gmx, smn, smx);
    float scale = fmaxf(gmx - gmn, 1e-8f) / 63.0f;
    for (int i = threadIdx.x; i < n; i += blockDim.x) {
        float v = src[i];
        dst[i] = rintf((v - gmn) / scale) * scale + gmn;
    }
}

// ONE prep launch (47 blocks):
//   0..9   : quantize weight/bias tensors into ws
//   10..20 : grid argmax tables
//   21..44 : weight fragments, layers 1..3 (self-contained minmax)
//   45     : weight fragments, layer 0 (4 waves; K rows 5..31 zero)
//   46     : w4 f16-pair pack (x64 scaled)
__global__ void vinr_prep(
    const float* __restrict__ cb0, const float* __restrict__ ind0,
    const float* __restrict__ cb1, const float* __restrict__ ind1,
    const float* __restrict__ cb2, const float* __restrict__ ind2,
    const float* __restrict__ w0, const float* __restrict__ b0,
    const float* __restrict__ w1, const float* __restrict__ b1,
    const float* __restrict__ w2, const float* __restrict__ b2,
    const float* __restrict__ w3, const float* __restrict__ b3,
    const float* __restrict__ w4, const float* __restrict__ b4,
    float* __restrict__ ws)
{
    __shared__ float smn[4], smx[4];
    if (blockIdx.x < 10) {
        switch (blockIdx.x) {
            case 0: quantize_tensor(w0, 320, ws + WQ0, smn, smx); break;
            case 1: quantize_tensor(b0, 64, ws + BQ0, smn, smx); break;
            case 2: quantize_tensor(w1, 4096, ws + WQ1, smn, smx); break;
            case 3: quantize_tensor(b1, 64, ws + BQ1, smn, smx); break;
            case 4: quantize_tensor(w2, 4096, ws + WQ2, smn, smx); break;
            case 5: quantize_tensor(b2, 64, ws + BQ2, smn, smx); break;
            case 6: quantize_tensor(w3, 4096, ws + WQ3, smn, smx); break;
            case 7: quantize_tensor(b3, 64, ws + BQ3, smn, smx); break;
            case 8: quantize_tensor(w4, 64, ws + WQ4, smn, smx); break;
            case 9: quantize_tensor(b4, 1, ws + BQ4, smn, smx); break;
        }
    } else if (blockIdx.x < 21) {
        int r = (int)(blockIdx.x - 10) * 256 + (int)threadIdx.x;
        const float* ind = nullptr; const float* cb = nullptr; float* dst = nullptr;
        if (r < 128)       { ind = ind0 + r * 64;          cb = cb0; dst = ws + GT0 + r * 4; }
        else if (r < 640)  { int rr = r - 128;  ind = ind1 + rr * 64; cb = cb1; dst = ws + GT1 + rr * 4; }
        else if (r < 2688) { int rr = r - 640;  ind = ind2 + rr * 64; cb = cb2; dst = ws + GT2 + rr * 4; }
        if (dst) {
            float best = -3.4e38f; int bi = 0;
            for (int j = 0; j < 64; ++j) {
                float v = ind[j];
                if (v > best) { best = v; bi = j; }
            }
            #pragma unroll
            for (int d = 0; d < 4; ++d) dst[d] = cb[bi * 4 + d];
        }
    } else if (blockIdx.x < 45) {
        if (threadIdx.x < 64) {                        // one wave per frag
            int fi = (int)blockIdx.x - 21;             // 0..23
            int lane = (int)threadIdx.x;
            int l = fi >> 3, s = (fi >> 2) & 1, ft = fi & 3;
            const float* w = (l == 0) ? w1 : (l == 1) ? w2 : w3;
            float mn = 3.4e38f, mx = -3.4e38f;
            for (int i = lane; i < 4096; i += 64) {
                float v = w[i];
                mn = fminf(mn, v); mx = fmaxf(mx, v);
            }
            #pragma unroll
            for (int off = 32; off > 0; off >>= 1) {
                mn = fminf(mn, __shfl_xor(mn, off));
                mx = fmaxf(mx, __shfl_xor(mx, off));
            }
            float scale = fmaxf(mx - mn, 1e-8f) / 63.0f;
            int q = lane >> 4, m15 = lane & 15;
            int n = ft * 16 + m15;
            f16x8 hi;
            #pragma unroll
            for (int j = 0; j < 8; ++j) {
                int k = s * 32 + q * 8 + j;
                float v = w[k * 64 + n];
                v = (rintf((v - mn) / scale) * scale + mn) * WSCALE;
                hi[j] = (_Float16)v;
            }
            f16x8* base = (f16x8*)(ws + FRAG_OFF);
            base[fi * 64 + lane] = hi;
        }
    } else if (blockIdx.x == 45) {
        // layer-0 frags: wave wv -> ft wv; W0 is [5][64], K padded to 32 with zeros.
        int wv = (int)threadIdx.x >> 6;
        int lane = (int)threadIdx.x & 63;
        if (wv < 4) {
            float mn = 3.4e38f, mx = -3.4e38f;
            for (int i = lane; i < 320; i += 64) {
                float v = w0[i];
                mn = fminf(mn, v); mx = fmaxf(mx, v);
            }
            #pragma unroll
            for (int off = 32; off > 0; off >>= 1) {
                mn = fminf(mn, __shfl_xor(mn, off));
                mx = fmaxf(mx, __shfl_xor(mx, off));
            }
            float scale = fmaxf(mx - mn, 1e-8f) / 63.0f;
            int q = lane >> 4, m15 = lane & 15;
            int n = wv * 16 + m15;
            f16x8 hi;
            #pragma unroll
            for (int j = 0; j < 8; ++j) {
                int k = q * 8 + j;
                float v = 0.0f;
                if (k < 5) {
                    float vv = w0[k * 64 + n];
                    v = (rintf((vv - mn) / scale) * scale + mn) * WSCALE;
                }
                hi[j] = (_Float16)v;
            }
            f16x8* base = (f16x8*)(ws + FRAG_OFF);
            base[(24 + wv) * 64 + lane] = hi;
        }
    } else {
        // w4 pack: quantize (self-contained minmax), scale x64, single f16 pairs.
        if (threadIdx.x < 64) {
            int lane = (int)threadIdx.x;
            float v = w4[lane];
            float mn = v, mx = v;
            #pragma unroll
            for (int off = 32; off > 0; off >>= 1) {
                mn = fminf(mn, __shfl_xor(mn, off));
                mx = fmaxf(mx, __shfl_xor(mx, off));
            }
            float scale = fmaxf(mx - mn, 1e-8f) / 63.0f;
            if (lane < 32) {
                float q0 = (rintf((w4[2 * lane] - mn) / scale) * scale + mn) * WSCALE;
                float q1 = (rintf((w4[2 * lane + 1] - mn) / scale) * scale + mn) * WSCALE;
                unsigned int* wsU = (unsigned int*)ws;
                wsU[W4P + lane] = pack_f16(q0, q1);   // single RNE f16
            }
        }
    }
}

// 32 points per wave; activations in LDS as packed f16 pairs in B-frag pair
// order (row/point stride 38 u32, zero measured conflicts). Weights: single
// RNE f16 (x64-scaled hi frags), 56 MFMAs/wave-pass. Layer loop fully
// unrolled. launch_bounds (256,4): r16 showed (256,8) forces VGPR 48->32
// with ~38 MB/dispatch scratch spill for zero time gain.
#define PSTR 38

__global__ __launch_bounds__(256, 4) void vinr_main(
    const float* __restrict__ x, const float* __restrict__ ws,
    float* __restrict__ out, int N)
{
    __shared__ __align__(16) unsigned int hlds[4 * 32 * PSTR];
    int wave = threadIdx.x >> 6, lane = threadIdx.x & 63;
    int q = lane >> 4, m15 = lane & 15;
    int p = lane & 31, half = lane >> 5;
    unsigned int* slice = hlds + wave * (32 * PSTR);

    int idx = (int)blockIdx.x * 128 + wave * 32 + p;
    int idxc = min(idx, N - 1);
    float2 xr = ((const float2*)x)[idxc];
    float feat  = xr.x;
    float coord = xr.y;

    float g0 = 0.f, g1 = 0.f, g2 = 0.f, g3 = 0.f;
    const int RES[3]  = {128, 512, 2048};
    const int GOFF[3] = {GT0, GT1, GT2};
    #pragma unroll
    for (int gi = 0; gi < 3; ++gi) {
        int res = RES[gi];
        float c = (coord + 1.0f) * 0.5f * (float)(res - 1);
        int left  = min((int)floorf(c), res - 2);
        int right = max((int)ceilf(c), 1);
        float w = c - (float)left;
        const float4* gt = (const float4*)(ws + GOFF[gi]);
        float4 gl = gt[left];
        float4 gr = gt[right];
        float wm = 1.0f - w;
        g0 += wm * gl.x + w * gr.x;
        g1 += wm * gl.y + w * gr.y;
        g2 += wm * gl.z + w * gr.z;
        g3 += wm * gl.w + w * gr.w;
    }

    const f16x8* fh = (const f16x8*)(ws + FRAG_OFF);
    f16x8 zfrag = __builtin_bit_cast(f16x8, (uintx4){0u, 0u, 0u, 0u});

    // stage layer-0 B inputs as f16 pairs: row p slots 0..3 (half 0 only).
    if (half == 0) {
        unsigned int* row = slice + p * PSTR;
        *(uint2*)row       = make_uint2(pack_f16(g0, g1), pack_f16(g2, g3));
        *(uint2*)(row + 2) = make_uint2(pack_f16(feat, 0.0f), 0u);
    }

    // ---- layer 0 (5 -> 64): A = 64*W0^T hi frags (K rows >=5 zero), B = inputs.
    {
        f16x8 Wh[4];
        #pragma unroll
        for (int ft = 0; ft < 4; ++ft)
            Wh[ft] = fh[(24 + ft) * 64 + lane];
        f16x8 B[2];
        #pragma unroll
        for (int pt = 0; pt < 2; ++pt) {
            B[pt] = zfrag;
            if (q == 0) {
                const unsigned int* rp = slice + (pt * 16 + m15) * PSTR;
                B[pt] = frag_from(*(const uint2*)rp, *(const uint2*)(rp + 2));
            }
        }
        floatx4 acc[4][2];
        #pragma unroll
        for (int ft = 0; ft < 4; ++ft)
            #pragma unroll
            for (int pt = 0; pt < 2; ++pt)
                acc[ft][pt] = (floatx4){0.f, 0.f, 0.f, 0.f};
        #pragma unroll
        for (int ft = 0; ft < 4; ++ft)
            #pragma unroll
            for (int pt = 0; pt < 2; ++pt)
                acc[ft][pt] = mfma16(Wh[ft], B[pt], acc[ft][pt]);
        #pragma unroll
        for (int ft = 0; ft < 4; ++ft) {
            float4 b4 = *(const float4*)(ws + BQ0 + ft * 16 + q * 4);
            #pragma unroll
            for (int pt = 0; pt < 2; ++pt) {
                floatx4 av = acc[ft][pt];
                floatx2 a01 = __builtin_elementwise_fma((floatx2){av[0], av[1]},
                                  splat2(WINV), (floatx2){b4.x, b4.y});
                floatx2 a23 = __builtin_elementwise_fma((floatx2){av[2], av[3]},
                                  splat2(WINV), (floatx2){b4.z, b4.w});
                floatx2 v01 = gelu2(a01);
                floatx2 v23 = gelu2(a23);
                *(uint2*)(slice + (pt * 16 + m15) * PSTR + 8 * ft + 2 * q) =
                    make_uint2(pkrtz(v01.x, v01.y), pkrtz(v23.x, v23.y));
            }
        }
    }

    // ---- layers 1..3 (fully unrolled)
    const int BQL[3] = {BQ1, BQ2, BQ3};
    #pragma unroll
    for (int l = 0; l < 3; ++l) {
        floatx4 acc[4][2];
        #pragma unroll
        for (int ft = 0; ft < 4; ++ft)
            #pragma unroll
            for (int pt = 0; pt < 2; ++pt)
                acc[ft][pt] = (floatx4){0.f, 0.f, 0.f, 0.f};

        #pragma unroll
        for (int s = 0; s < 2; ++s) {
            f16x8 Wh[4];
            #pragma unroll
            for (int ft = 0; ft < 4; ++ft)
                Wh[ft] = fh[((l * 2 + s) * 4 + ft) * 64 + lane];
            f16x8 B[2];
            #pragma unroll
            for (int pt = 0; pt < 2; ++pt) {
                const unsigned int* rp =
                    slice + (pt * 16 + m15) * PSTR + 16 * s + 4 * q;
                B[pt] = frag_from(*(const uint2*)rp, *(const uint2*)(rp + 2));
            }
            #pragma unroll
            for (int ft = 0; ft < 4; ++ft)
                #pragma unroll
                for (int pt = 0; pt < 2; ++pt)
                    acc[ft][pt] = mfma16(Wh[ft], B[pt], acc[ft][pt]);
        }
        #pragma unroll
        for (int ft = 0; ft < 4; ++ft) {
            float4 b4 = *(const float4*)(ws + BQL[l] + ft * 16 + q * 4);
            #pragma unroll
            for (int pt = 0; pt < 2; ++pt) {
                floatx4 av = acc[ft][pt];
                floatx2 a01 = __builtin_elementwise_fma((floatx2){av[0], av[1]},
                                  splat2(WINV), (floatx2){b4.x, b4.y});
                floatx2 a23 = __builtin_elementwise_fma((floatx2){av[2], av[3]},
                                  splat2(WINV), (floatx2){b4.z, b4.w});
                floatx2 v01 = gelu2(a01);
                floatx2 v23 = gelu2(a23);
                *(uint2*)(slice + (pt * 16 + m15) * PSTR + 8 * ft + 2 * q) =
                    make_uint2(pkrtz(v01.x, v01.y), pkrtz(v23.x, v23.y));
            }
        }
    }

    // layer 4: half-dot over f16 pairs via v_dot2_f32_f16, combine via shfl.
    {
        const unsigned int* wsU = (const unsigned int*)ws;
        const unsigned int* base = slice + p * PSTR + 16 * half;
        int wb = W4P + 16 * half;
        float ah = 0.0f;
        #pragma unroll
        for (int c = 0; c < 8; ++c) {
            uint2 r = *(const uint2*)(base + 2 * c);
            ah = fdot2f(h2(r.x), h2(wsU[wb + 2 * c]),     ah);
            ah = fdot2f(h2(r.y), h2(wsU[wb + 2 * c + 1]), ah);
        }
        float acc4 = fmaf(ah, WINV, (half == 0) ? ws[BQ4] : 0.0f);
        acc4 += __shfl_xor(acc4, 32);
        if (half == 0 && idx < N) out[idx] = tanh_fast(acc4);
    }
}

extern "C" void kernel_launch(void* const* d_in, const int* in_sizes, int n_in,
                              void* d_out, int out_size, void* d_ws, size_t ws_size,
                              hipStream_t stream) {
    const float* x    = (const float*)d_in[0];
    const float* cb0  = (const float*)d_in[1];
    const float* ind0 = (const float*)d_in[2];
    const float* cb1  = (const float*)d_in[3];
    const float* ind1 = (const float*)d_in[4];
    const float* cb2  = (const float*)d_in[5];
    const float* ind2 = (const float*)d_in[6];
    const float* w0 = (const float*)d_in[7],  * b0 = (const float*)d_in[8];
    const float* w1 = (const float*)d_in[9],  * b1 = (const float*)d_in[10];
    const float* w2 = (const float*)d_in[11], * b2 = (const float*)d_in[12];
    const float* w3 = (const float*)d_in[13], * b3 = (const float*)d_in[14];
    const float* w4 = (const float*)d_in[15], * b4 = (const float*)d_in[16];
    float* ws  = (float*)d_ws;
    float* out = (float*)d_out;

    int N = in_sizes[0] / 2;  // 1<<20

    vinr_prep<<<47, 256, 0, stream>>>(cb0, ind0, cb1, ind1, cb2, ind2,
                                      w0, b0, w1, b1, w2, b2, w3, b3, w4, b4, ws);
    int blocks = (N + 127) / 128;
    vinr_main<<<blocks, 256, 0, stream>>>(x, ws, out, N);
}